// Round 1
// baseline (314.410 us; speedup 1.0000x reference)
//
#include <hip/hip_runtime.h>
#include <hip/hip_bf16.h>

#define CIN   256
#define COUT  256
#define HH    56
#define WW    56
#define NB    32
#define KTOT  2304            // 3*3*256
#define MTOT  (NB * HH * WW)  // 100352

#define BM 128
#define BN 128
#define BK 64
#define NTHREADS 256

typedef __attribute__((ext_vector_type(4))) float  f32x4;
typedef __attribute__((ext_vector_type(8))) __bf16 bf16x8;

// ---- Kernel 1: binarize W (KH,KW,CIN,COUT) fp32 -> Bt[cout][k] bf16 (+-1) ----
__global__ void binarize_w_kernel(const float* __restrict__ W,
                                  unsigned short* __restrict__ bt) {
    int k  = blockIdx.x;    // 0..KTOT-1  (k = (kh*3+kw)*256 + cin)
    int co = threadIdx.x;   // 0..COUT-1
    float w = W[(size_t)k * COUT + co];
    // jnp.sign: +1 / -1 / 0  (bf16 bit patterns)
    unsigned short s = (w > 0.f) ? 0x3F80u : ((w < 0.f) ? 0xBF80u : 0u);
    bt[(size_t)co * KTOT + k] = s;
}

__device__ __forceinline__ void gload_lds16(const void* g, void* l) {
    __builtin_amdgcn_global_load_lds(
        (const __attribute__((address_space(1))) void*)g,
        (__attribute__((address_space(3))) void*)l,
        16, 0, 0);
}

// ---- Kernel 2: implicit-GEMM binary conv, bf16 MFMA, fp32 accum ----
__global__ __launch_bounds__(NTHREADS, 2)
void bconv_kernel(const float* __restrict__ x,
                  const unsigned short* __restrict__ bt,
                  const float* __restrict__ bias,
                  float* __restrict__ out) {
    __shared__ __bf16 Al[BM][BK];   // 16 KB, A tile (rows = output positions)
    __shared__ __bf16 Bl[BN][BK];   // 16 KB, B^T tile (rows = couts)

    const int tid  = threadIdx.x;
    const int lane = tid & 63;
    const int wid  = tid >> 6;

    const int m_base = blockIdx.x * BM;
    const int n_base = blockIdx.y * BN;

    // 4 waves in 2x2; each wave owns a 64x64 output sub-tile
    const int wm = (wid >> 1) * 64;
    const int wn = (wid & 1) * 64;

    // --- A-staging precompute: this thread stages rows p*32+(tid>>3), col-group tid&7 ---
    const int cg = tid & 7;
    int hh_[4], ww_[4], rrow_[4];
    size_t xoff_[4];
#pragma unroll
    for (int p = 0; p < 4; ++p) {
        int r = p * 32 + (tid >> 3);
        rrow_[p] = r;
        int flat = m_base + r;               // flat = (n*56 + h)*56 + w
        ww_[p] = flat % WW;
        hh_[p] = (flat / WW) % HH;
        xoff_[p] = (size_t)flat * CIN;
    }

    f32x4 acc[4][4];
#pragma unroll
    for (int i = 0; i < 4; ++i)
#pragma unroll
        for (int j = 0; j < 4; ++j)
            acc[i][j] = (f32x4){0.f, 0.f, 0.f, 0.f};

    const int nsteps = KTOT / BK;  // 36 = 9 taps * 4 cin-chunks
    for (int ks = 0; ks < nsteps; ++ks) {
        const int t  = ks >> 2;         // tap 0..8
        const int dh = t / 3 - 1;
        const int dw = t % 3 - 1;
        const int c0 = (ks & 3) * 64 + cg * 8;  // cin offset for this thread

        __syncthreads();   // previous compute done before LDS overwrite

        // --- B staging: global_load_lds, 16B/lane; wave w covers rows w*32..w*32+31 ---
        {
            const int rb = wid * 32;
#pragma unroll
            for (int i = 0; i < 4; ++i) {
                int row0 = rb + i * 8;
                const unsigned short* g = bt
                    + (size_t)(n_base + row0 + (lane >> 3)) * KTOT
                    + ks * 64 + (lane & 7) * 8;
                gload_lds16(g, &Bl[row0][0]);
            }
        }

        // --- A staging: fp32 global (predicated for SAME padding) -> bf16 -> LDS ---
#pragma unroll
        for (int p = 0; p < 4; ++p) {
            int ih = hh_[p] + dh;
            int iw = ww_[p] + dw;
            f32x4 v0 = (f32x4){0.f, 0.f, 0.f, 0.f};
            f32x4 v1 = (f32x4){0.f, 0.f, 0.f, 0.f};
            if ((unsigned)ih < (unsigned)HH && (unsigned)iw < (unsigned)WW) {
                const float* gp = x + xoff_[p] + (dh * WW + dw) * CIN + c0;
                v0 = *(const f32x4*)gp;
                v1 = *(const f32x4*)(gp + 4);
            }
            bf16x8 ov;
            ov[0] = (__bf16)v0[0]; ov[1] = (__bf16)v0[1];
            ov[2] = (__bf16)v0[2]; ov[3] = (__bf16)v0[3];
            ov[4] = (__bf16)v1[0]; ov[5] = (__bf16)v1[1];
            ov[6] = (__bf16)v1[2]; ov[7] = (__bf16)v1[3];
            *(bf16x8*)&Al[rrow_[p]][cg * 8] = ov;
        }

        __syncthreads();   // drains vmcnt(0) for global_load_lds + lgkmcnt

        // --- MFMA: 2 k-chunks of 32, 16 MFMAs each ---
#pragma unroll
        for (int kk = 0; kk < 2; ++kk) {
            const int kb = kk * 32 + (lane >> 4) * 8;
            bf16x8 af[4], bfr[4];
#pragma unroll
            for (int mi = 0; mi < 4; ++mi)
                af[mi] = *(const bf16x8*)&Al[wm + mi * 16 + (lane & 15)][kb];
#pragma unroll
            for (int ni = 0; ni < 4; ++ni)
                bfr[ni] = *(const bf16x8*)&Bl[wn + ni * 16 + (lane & 15)][kb];
#pragma unroll
            for (int mi = 0; mi < 4; ++mi)
#pragma unroll
                for (int ni = 0; ni < 4; ++ni)
                    acc[mi][ni] = __builtin_amdgcn_mfma_f32_16x16x32_bf16(
                        af[mi], bfr[ni], acc[mi][ni], 0, 0, 0);
        }
    }

    // --- epilogue: bias + ReLU, fp32 stores (16-lane col groups coalesce) ---
    // C/D layout (m89): col = lane&15, row = (lane>>4)*4 + j
    const int col_l  = lane & 15;
    const int row_g4 = (lane >> 4) * 4;
#pragma unroll
    for (int ni = 0; ni < 4; ++ni) {
        const int cout = n_base + wn + ni * 16 + col_l;
        const float bv = bias[cout];
#pragma unroll
        for (int mi = 0; mi < 4; ++mi) {
            const int row = m_base + wm + mi * 16 + row_g4;
#pragma unroll
            for (int j = 0; j < 4; ++j) {
                float v = acc[mi][ni][j] + bv;
                out[(size_t)(row + j) * COUT + cout] = v > 0.f ? v : 0.f;
            }
        }
    }
}

extern "C" void kernel_launch(void* const* d_in, const int* in_sizes, int n_in,
                              void* d_out, int out_size, void* d_ws, size_t ws_size,
                              hipStream_t stream) {
    const float* x = (const float*)d_in[0];   // (32,56,56,256) fp32
    const float* W = (const float*)d_in[1];   // (3,3,256,256) fp32
    const float* b = (const float*)d_in[2];   // (256,) fp32
    float* out = (float*)d_out;               // (32,56,56,256) fp32
    unsigned short* bt = (unsigned short*)d_ws;  // B^T bf16: COUT*KTOT*2 = 1.18 MB

    binarize_w_kernel<<<dim3(KTOT), dim3(COUT), 0, stream>>>(W, bt);
    bconv_kernel<<<dim3(MTOT / BM, COUT / BN), dim3(NTHREADS), 0, stream>>>(x, bt, b, out);
}

// Round 2
// 151.507 us; speedup vs baseline: 2.0752x; 2.0752x over previous
//
#include <hip/hip_runtime.h>
#include <hip/hip_bf16.h>

#define CIN   256
#define COUT  256
#define HH    56
#define WW    56
#define NB    32
#define KTOT  2304            // 3*3*256
#define MTOT  (NB * HH * WW)  // 100352

#define BM 128
#define BN 256
#define BK 64
#define NTHREADS 512
#define NSTEPS (KTOT / BK)    // 36 = 4 cin-chunks * 9 taps

#define BT_BYTES  ((size_t)COUT * KTOT * 2)   // 1,179,648
#define XB_OFF    BT_BYTES
#define XB_BYTES  ((size_t)MTOT * CIN * 2)    // 51,380,224
#define ZB_OFF    (XB_OFF + XB_BYTES)
#define WS_NEEDED (ZB_OFF + 64)

typedef __attribute__((ext_vector_type(4))) float  f32x4;
typedef __attribute__((ext_vector_type(8))) __bf16 bf16x8;

// ---- x fp32 -> bf16 cast (and zero-page init) ----
__global__ void xcast_kernel(const float* __restrict__ x, __bf16* __restrict__ xb,
                             float* __restrict__ zbuf) {
    const size_t total = (size_t)MTOT * CIN / 8;
    size_t idx = (size_t)blockIdx.x * blockDim.x + threadIdx.x;
    const size_t stride = (size_t)gridDim.x * blockDim.x;
    for (size_t g = idx; g < total; g += stride) {
        f32x4 v0 = ((const f32x4*)x)[2 * g];
        f32x4 v1 = ((const f32x4*)x)[2 * g + 1];
        bf16x8 o;
        o[0] = (__bf16)v0[0]; o[1] = (__bf16)v0[1];
        o[2] = (__bf16)v0[2]; o[3] = (__bf16)v0[3];
        o[4] = (__bf16)v1[0]; o[5] = (__bf16)v1[1];
        o[6] = (__bf16)v1[2]; o[7] = (__bf16)v1[3];
        ((bf16x8*)xb)[g] = o;
    }
    if (blockIdx.x == 0 && threadIdx.x < 16) zbuf[threadIdx.x] = 0.f;
}

// ---- binarize W (tap,cin,cout) -> bt[cout][ks*64 + swizzled ci] bf16 {+-1,0} ----
// K-order: ks = cin_chunk*9 + tap (taps innermost in the conv K-loop).
// Pre-swizzled so conv's linear global_load_lds yields the XOR-swizzled LDS tile.
__global__ void binarize_w_kernel(const float* __restrict__ W,
                                  unsigned short* __restrict__ bt) {
    int k  = blockIdx.x;    // tap*256 + cin
    int co = threadIdx.x;
    int tap = k >> 8, cin = k & 255;
    int c = cin >> 6, ci = cin & 63;
    int ks = c * 9 + tap;
    float w = W[(size_t)k * COUT + co];
    unsigned short s = (w > 0.f) ? 0x3F80u : ((w < 0.f) ? 0xBF80u : 0u);
    bt[(size_t)co * KTOT + ks * 64 + (ci ^ ((co & 7) << 3))] = s;
}

__device__ __forceinline__ void gload_lds16(const void* g, void* l) {
    __builtin_amdgcn_global_load_lds(
        (const __attribute__((address_space(1))) void*)g,
        (__attribute__((address_space(3))) void*)l,
        16, 0, 0);
}

// ---- implicit-GEMM binary conv; 128x256 tile, 8 waves (2M x 4N), BK=64 ----
template<int USE_XB>
__global__ __launch_bounds__(NTHREADS, 4)
void bconv_kernel(const float* __restrict__ x,
                  const __bf16* __restrict__ xb,
                  const unsigned short* __restrict__ bt,
                  const float* __restrict__ bias,
                  float* __restrict__ out,
                  const char* __restrict__ zb) {
    __shared__ __bf16 Al[BM][BK];   // 16 KB (XOR-swizzled rows)
    __shared__ __bf16 Bl[BN][BK];   // 32 KB (XOR-swizzled rows)

    const int tid  = threadIdx.x;
    const int lane = tid & 63;
    const int wid  = tid >> 6;

    // XCD-aware bijective swizzle: 784 = 8 * 98
    const int bid = blockIdx.x;
    const int swz = (bid & 7) * (MTOT / BM / 8) + (bid >> 3);
    const int m_base = swz * BM;

    const int wm = (wid & 1) * 64;        // 2 waves in M
    const int wn = (wid >> 1) * 64;       // 4 waves in N

    // B staging: 4 gload_lds/wave, rows wid*32 + i*8 + (lane>>3), linear (pre-swizzled)
    const int  rB0 = wid * 32 + (lane >> 3);
    const long bB0 = (long)rB0 * (KTOT * 2) + (lane & 7) * 16;

    // A staging precompute (per thread, 2 rows)
    int aH[2], aW[2], aOff[2];
    if (USE_XB) {
        const int chunk = (lane & 7) ^ ((lane >> 3) & 7);  // source pre-swizzle
#pragma unroll
        for (int i = 0; i < 2; ++i) {
            int r = (wid * 2 + i) * 8 + (lane >> 3);
            int flat = m_base + r;
            aW[i] = flat % WW;
            aH[i] = (flat / WW) % HH;
            aOff[i] = flat * (CIN * 2) + chunk * 16;   // bytes into xb
        }
    } else {
#pragma unroll
        for (int i = 0; i < 2; ++i) {
            int r = i * 64 + (tid >> 3);
            int flat = m_base + r;
            aW[i] = flat % WW;
            aH[i] = (flat / WW) % HH;
            aOff[i] = flat * (CIN * 4);                // bytes into x (fp32)
        }
    }

    f32x4 acc[4][4];
#pragma unroll
    for (int i = 0; i < 4; ++i)
#pragma unroll
        for (int j = 0; j < 4; ++j)
            acc[i][j] = (f32x4){0.f, 0.f, 0.f, 0.f};

    const char* xbb = (const char*)xb;
    const char* xfb = (const char*)x;
    const char* btb = (const char*)bt;

    for (int ks = 0; ks < NSTEPS; ++ks) {
        const int c    = ks / 9;          // cin chunk
        const int tap  = ks % 9;          // taps innermost -> L1/L2 catch tap reuse
        const int dh   = tap / 3 - 1;
        const int dw   = tap % 3 - 1;
        const int doff = dh * WW + dw;

        __syncthreads();   // previous compute done before LDS overwrite

        // --- B staging (linear; bt is pre-swizzled) ---
#pragma unroll
        for (int i = 0; i < 4; ++i) {
            const char* g = btb + bB0 + (long)i * 8 * (KTOT * 2) + ks * 128;
            gload_lds16(g, &Bl[wid * 32 + i * 8][0]);
        }

        // --- A staging ---
        if (USE_XB) {
#pragma unroll
            for (int i = 0; i < 2; ++i) {
                int ih = aH[i] + dh, iw = aW[i] + dw;
                bool valid = ((unsigned)ih < (unsigned)HH) && ((unsigned)iw < (unsigned)WW);
                const char* g = valid ? (xbb + (long)(aOff[i] + doff * (CIN * 2) + c * 128))
                                      : zb;
                gload_lds16(g, &Al[(wid * 2 + i) * 8][0]);
            }
        } else {
            const int cg = tid & 7;
#pragma unroll
            for (int i = 0; i < 2; ++i) {
                int ih = aH[i] + dh, iw = aW[i] + dw;
                f32x4 v0 = (f32x4){0.f, 0.f, 0.f, 0.f};
                f32x4 v1 = (f32x4){0.f, 0.f, 0.f, 0.f};
                if (((unsigned)ih < (unsigned)HH) && ((unsigned)iw < (unsigned)WW)) {
                    const float* gp = (const float*)(xfb +
                        (long)(aOff[i] + doff * (CIN * 4) + c * 256 + cg * 32));
                    v0 = ((const f32x4*)gp)[0];
                    v1 = ((const f32x4*)gp)[1];
                }
                bf16x8 o;
                o[0] = (__bf16)v0[0]; o[1] = (__bf16)v0[1];
                o[2] = (__bf16)v0[2]; o[3] = (__bf16)v0[3];
                o[4] = (__bf16)v1[0]; o[5] = (__bf16)v1[1];
                o[6] = (__bf16)v1[2]; o[7] = (__bf16)v1[3];
                int r = i * 64 + (tid >> 3);
                *(bf16x8*)((char*)&Al[0][0] + r * 128 + ((cg * 16) ^ ((r & 7) << 4))) = o;
            }
        }

        __syncthreads();   // drains vmcnt(0)+lgkmcnt for staging

        // --- MFMA: 2 k-chunks of 32, swizzled fragment reads ---
        const char* Ab = (const char*)&Al[0][0];
        const char* Bb = (const char*)&Bl[0][0];
        const int swzr = (lane & 7) << 4;
        const int rsel = lane & 15;
        const int csel = (lane >> 4) * 16;
#pragma unroll
        for (int kk = 0; kk < 2; ++kk) {
            const int colb = kk * 64 + csel;
            bf16x8 af[4], bfr[4];
#pragma unroll
            for (int mi = 0; mi < 4; ++mi)
                af[mi] = *(const bf16x8*)(Ab + (wm + mi * 16 + rsel) * 128 + (colb ^ swzr));
#pragma unroll
            for (int ni = 0; ni < 4; ++ni)
                bfr[ni] = *(const bf16x8*)(Bb + (wn + ni * 16 + rsel) * 128 + (colb ^ swzr));
#pragma unroll
            for (int mi = 0; mi < 4; ++mi)
#pragma unroll
                for (int ni = 0; ni < 4; ++ni)
                    acc[mi][ni] = __builtin_amdgcn_mfma_f32_16x16x32_bf16(
                        af[mi], bfr[ni], acc[mi][ni], 0, 0, 0);
        }
    }

    // --- epilogue: bias + ReLU ---
    // C/D layout: col = lane&15, row = (lane>>4)*4 + j
    const int col_l  = lane & 15;
    const int row_g4 = (lane >> 4) * 4;
#pragma unroll
    for (int ni = 0; ni < 4; ++ni) {
        const int cout = wn + ni * 16 + col_l;
        const float bv = bias[cout];
#pragma unroll
        for (int mi = 0; mi < 4; ++mi) {
            const int row = m_base + wm + mi * 16 + row_g4;
#pragma unroll
            for (int j = 0; j < 4; ++j) {
                float v = acc[mi][ni][j] + bv;
                out[(size_t)(row + j) * COUT + cout] = v > 0.f ? v : 0.f;
            }
        }
    }
}

extern "C" void kernel_launch(void* const* d_in, const int* in_sizes, int n_in,
                              void* d_out, int out_size, void* d_ws, size_t ws_size,
                              hipStream_t stream) {
    const float* x = (const float*)d_in[0];   // (32,56,56,256) fp32
    const float* W = (const float*)d_in[1];   // (3,3,256,256) fp32
    const float* b = (const float*)d_in[2];   // (256,) fp32
    float* out = (float*)d_out;

    char* ws = (char*)d_ws;
    unsigned short* bt = (unsigned short*)ws;
    __bf16* xb   = (__bf16*)(ws + XB_OFF);
    float*  zbuf = (float*)(ws + ZB_OFF);

    const bool use_xb = (ws_size >= WS_NEEDED);

    binarize_w_kernel<<<dim3(KTOT), dim3(COUT), 0, stream>>>(W, bt);
    if (use_xb) {
        xcast_kernel<<<dim3(2048), dim3(256), 0, stream>>>(x, xb, zbuf);
        bconv_kernel<1><<<dim3(MTOT / BM), dim3(NTHREADS), 0, stream>>>(
            x, xb, bt, b, out, (const char*)zbuf);
    } else {
        bconv_kernel<0><<<dim3(MTOT / BM), dim3(NTHREADS), 0, stream>>>(
            x, xb, bt, b, out, nullptr);
    }
}